// Round 1
// baseline (1605.680 us; speedup 1.0000x reference)
//
#include <hip/hip_runtime.h>
#include <math.h>

// ---------------------------------------------------------------------------
// fp32 tiled GEMM: C = alpha * A @ B   (TRANSB=0: B is [K][N] row-major;
//                                       TRANSB=1: B is [N][K] row-major, i.e. C=A@B^T)
// Tile 128x128, BK=8, 256 threads, 8x8 micro-tile per thread.
// A is staged transposed into LDS (As[k][m]) so fragment reads are b128.
// blockIdx.z selects a batch via the given pointer strides.
// Assumes M,N % 128 == 0 and K % 8 == 0 (true for all shapes used here).
// ---------------------------------------------------------------------------
#define TS 128
#define BK 8

template<int TRANSB>
__global__ __launch_bounds__(256)
void gemm_f32(const float* __restrict__ Ag, const float* __restrict__ Bg,
              float* __restrict__ Cg, int M, int N, int K, float alpha,
              long sA, long sB, long sC)
{
    const float* A = Ag + (long)blockIdx.z * sA;
    const float* B = Bg + (long)blockIdx.z * sB;
    float*       C = Cg + (long)blockIdx.z * sC;

    __shared__ float As[BK][TS];
    __shared__ float Bs[BK][TS];

    const int tid  = threadIdx.x;
    const int brow = blockIdx.y * TS;
    const int bcol = blockIdx.x * TS;

    // A staging: thread -> (row, 4-wide k-chunk). 256 thr * 4 = 128*8 elems.
    const int arow = tid >> 1;          // 0..127
    const int ac4  = (tid & 1) * 4;     // 0 or 4
    // B staging (NN): thread -> (k-row, 4-wide n-chunk)
    const int bkr  = tid >> 5;          // 0..7
    const int bc4  = (tid & 31) * 4;    // 0..124

    // micro-tile coords: 16x16 threads, each 8x8 outputs
    const int tx   = tid & 15;
    const int ty   = tid >> 4;
    const int crow = ty * 8;
    const int ccol = tx * 8;

    float acc[8][8];
    #pragma unroll
    for (int i = 0; i < 8; ++i)
        #pragma unroll
        for (int j = 0; j < 8; ++j) acc[i][j] = 0.0f;

    for (int k0 = 0; k0 < K; k0 += BK) {
        // global loads first (overlap with previous tile's compute)
        float4 av = *(const float4*)(A + (long)(brow + arow) * K + k0 + ac4);
        float4 bv;
        if (TRANSB) {
            bv = *(const float4*)(B + (long)(bcol + arow) * K + k0 + ac4);
        } else {
            bv = *(const float4*)(B + (long)(k0 + bkr) * N + bcol + bc4);
        }
        __syncthreads();   // previous iteration's LDS reads done
        As[ac4 + 0][arow] = av.x;
        As[ac4 + 1][arow] = av.y;
        As[ac4 + 2][arow] = av.z;
        As[ac4 + 3][arow] = av.w;
        if (TRANSB) {
            Bs[ac4 + 0][arow] = bv.x;
            Bs[ac4 + 1][arow] = bv.y;
            Bs[ac4 + 2][arow] = bv.z;
            Bs[ac4 + 3][arow] = bv.w;
        } else {
            *(float4*)&Bs[bkr][bc4] = bv;
        }
        __syncthreads();

        #pragma unroll
        for (int k = 0; k < BK; ++k) {
            float4 a_lo = *(const float4*)&As[k][crow];
            float4 a_hi = *(const float4*)&As[k][crow + 4];
            float4 b_lo = *(const float4*)&Bs[k][ccol];
            float4 b_hi = *(const float4*)&Bs[k][ccol + 4];
            float a[8] = {a_lo.x, a_lo.y, a_lo.z, a_lo.w, a_hi.x, a_hi.y, a_hi.z, a_hi.w};
            float b[8] = {b_lo.x, b_lo.y, b_lo.z, b_lo.w, b_hi.x, b_hi.y, b_hi.z, b_hi.w};
            #pragma unroll
            for (int i = 0; i < 8; ++i)
                #pragma unroll
                for (int j = 0; j < 8; ++j)
                    acc[i][j] = fmaf(a[i], b[j], acc[i][j]);
        }
    }

    #pragma unroll
    for (int i = 0; i < 8; ++i) {
        float4 o0 = make_float4(acc[i][0] * alpha, acc[i][1] * alpha,
                                acc[i][2] * alpha, acc[i][3] * alpha);
        float4 o1 = make_float4(acc[i][4] * alpha, acc[i][5] * alpha,
                                acc[i][6] * alpha, acc[i][7] * alpha);
        float* cp = C + (long)(brow + crow + i) * N + bcol + ccol;
        *(float4*)(cp + 0) = o0;
        *(float4*)(cp + 4) = o1;
    }
}

// ---------------------------------------------------------------------------
// Row softmax for rows of length 2048. One 256-thread block per row;
// 8 elements per thread held in registers; two block reductions.
// ---------------------------------------------------------------------------
__global__ __launch_bounds__(256)
void softmax2048(float* __restrict__ S)
{
    float* row = S + (size_t)blockIdx.x * 2048;
    const int tid  = threadIdx.x;
    const int wave = tid >> 6;
    const int lane = tid & 63;

    float4 x0 = ((const float4*)row)[tid];
    float4 x1 = ((const float4*)row)[tid + 256];

    __shared__ float red[8];

    float m = fmaxf(fmaxf(fmaxf(x0.x, x0.y), fmaxf(x0.z, x0.w)),
                    fmaxf(fmaxf(x1.x, x1.y), fmaxf(x1.z, x1.w)));
    #pragma unroll
    for (int off = 32; off > 0; off >>= 1) m = fmaxf(m, __shfl_down(m, off));
    if (lane == 0) red[wave] = m;
    __syncthreads();
    m = fmaxf(fmaxf(red[0], red[1]), fmaxf(red[2], red[3]));

    x0.x = __expf(x0.x - m); x0.y = __expf(x0.y - m);
    x0.z = __expf(x0.z - m); x0.w = __expf(x0.w - m);
    x1.x = __expf(x1.x - m); x1.y = __expf(x1.y - m);
    x1.z = __expf(x1.z - m); x1.w = __expf(x1.w - m);

    float s = (x0.x + x0.y + x0.z + x0.w) + (x1.x + x1.y + x1.z + x1.w);
    #pragma unroll
    for (int off = 32; off > 0; off >>= 1) s += __shfl_down(s, off);
    if (lane == 0) red[4 + wave] = s;
    __syncthreads();
    s = (red[4] + red[5]) + (red[6] + red[7]);

    float inv = 1.0f / s;
    x0.x *= inv; x0.y *= inv; x0.z *= inv; x0.w *= inv;
    x1.x *= inv; x1.y *= inv; x1.z *= inv; x1.w *= inv;
    ((float4*)row)[tid]       = x0;
    ((float4*)row)[tid + 256] = x1;
}

// ---------------------------------------------------------------------------
// Launch: Q=q@Wq, K=k@Wk, V=v@Wv -> ws. Then per batch group:
//   S = (Q K^T)/32 -> ws scores; softmax rows; out = S @ V.
// ws: Q (32MB) | K (32MB) | V (32MB) | scores (16MB * batches_at_once)
// ---------------------------------------------------------------------------
extern "C" void kernel_launch(void* const* d_in, const int* in_sizes, int n_in,
                              void* d_out, int out_size, void* d_ws, size_t ws_size,
                              hipStream_t stream)
{
    const float* q  = (const float*)d_in[0];
    const float* k  = (const float*)d_in[1];
    const float* v  = (const float*)d_in[2];
    const float* Wq = (const float*)d_in[3];
    const float* Wk = (const float*)d_in[4];
    const float* Wv = (const float*)d_in[5];
    float* out = (float*)d_out;

    const int  Bn = 4, S = 2048, D = 1024;
    const long SD  = (long)S * D;       // 2,097,152
    const long MSD = (long)Bn * SD;     // 8,388,608 (all batches)
    const long SS  = (long)S * S;       // 4,194,304

    float* ws = (float*)d_ws;
    float* Qp = ws;
    float* Kp = ws + MSD;
    float* Vp = ws + 2 * MSD;
    float* Sb = ws + 3 * MSD;

    long avail = (long)(ws_size / sizeof(float)) - 3 * MSD;  // floats left for scores
    int nbat = (avail >= 4 * SS) ? 4 : ((avail >= 2 * SS) ? 2 : 1);

    dim3 blk(256);

    // Projections: [8192 x 1024] = [8192 x 1024] @ [1024 x 1024]
    dim3 gproj(1024 / TS, 8192 / TS, 1);
    gemm_f32<0><<<gproj, blk, 0, stream>>>(q, Wq, Qp, 8192, 1024, 1024, 1.0f, 0, 0, 0);
    gemm_f32<0><<<gproj, blk, 0, stream>>>(k, Wk, Kp, 8192, 1024, 1024, 1.0f, 0, 0, 0);
    gemm_f32<0><<<gproj, blk, 0, stream>>>(v, Wv, Vp, 8192, 1024, 1024, 1.0f, 0, 0, 0);

    for (int b0 = 0; b0 < Bn; b0 += nbat) {
        int nb = (Bn - b0 < nbat) ? (Bn - b0) : nbat;
        // scores = Q @ K^T / 32   [2048 x 2048], K-dim 1024
        gemm_f32<1><<<dim3(S / TS, S / TS, nb), blk, 0, stream>>>(
            Qp + b0 * SD, Kp + b0 * SD, Sb, S, S, D, 0.03125f, SD, SD, SS);
        // softmax rows
        softmax2048<<<dim3(S * nb), blk, 0, stream>>>(Sb);
        // out = P @ V   [2048 x 1024], K-dim 2048
        gemm_f32<0><<<dim3(D / TS, S / TS, nb), blk, 0, stream>>>(
            Sb, Vp + b0 * SD, out + b0 * SD, S, D, S, 1.0f, SS, SD, SD);
    }
}

// Round 2
// 565.422 us; speedup vs baseline: 2.8398x; 2.8398x over previous
//
#include <hip/hip_runtime.h>
#include <math.h>

typedef __attribute__((ext_vector_type(8))) short bfrag;   // 8 bf16 (4 VGPR)
typedef __attribute__((ext_vector_type(4))) float ffrag;   // 4 f32 acc
typedef __attribute__((ext_vector_type(4))) float f4;

__device__ __forceinline__ unsigned short f2bf(float x) {
    unsigned u = __float_as_uint(x);
    return (unsigned short)((u + 0x7fffu + ((u >> 16) & 1u)) >> 16);
}
__device__ __forceinline__ float bf2f(unsigned short h) {
    return __uint_as_float(((unsigned)h) << 16);
}

__device__ __forceinline__ void gload_lds16(const void* g, void* l) {
    __builtin_amdgcn_global_load_lds(
        (const __attribute__((address_space(1))) void*)g,
        (__attribute__((address_space(3))) void*)l,
        16, 0, 0);
}

// ---------------------------------------------------------------------------
// Split-bf16 GEMM: C = alpha * (A @ B^T), logical A[M][K], B[N][K] (K-major).
// A = Ah+Al, B = Bh+Bl; acc = Ah*Bh + Ah*Bl + Al*Bh (fp32 MFMA accum).
// AMODE 0: A is fp32, split in-kernel (reg-stage + ds_write).
// AMODE 1: A is bf16 hi/lo planes, staged via global_load_lds.
// EPI 0: C fp32 (alpha applied).  EPI 1: C as bf16 hi/lo planes [M][ldc].
// EPI 2: C transposed to hi/lo planes [1024][2048] per 2048-row batch (V^T).
// Tile 128x128, BK=32, 256 threads (4 waves, 2x2 of 64x64).
// LDS tile [128][32] bf16, row = 64B = 4 chunks of 16B; chunk' = chunk ^ ((row>>1)&3).
// ---------------------------------------------------------------------------
template<int AMODE, int EPI>
__global__ __launch_bounds__(256)
void gemm_split(const void* __restrict__ Ap, const void* __restrict__ Alp,
                long lda, long strideA,
                const unsigned short* __restrict__ Bhp, const unsigned short* __restrict__ Blp,
                long ldb, long strideB,
                void* __restrict__ Cp, void* __restrict__ Clp,
                long ldc, long strideC,
                int K, float alpha)
{
    __shared__ __align__(16) unsigned short Ash[4096];
    __shared__ __align__(16) unsigned short Asl[4096];
    __shared__ __align__(16) unsigned short Bsh[4096];
    __shared__ __align__(16) unsigned short Bsl[4096];

    const int tid  = threadIdx.x;
    const int lane = tid & 63;
    const int wave = tid >> 6;
    const int wr = wave >> 1, wc = wave & 1;
    const int fr = lane & 15, fq = lane >> 4;
    const long brow = (long)blockIdx.y * 128;
    const long bcol = (long)blockIdx.x * 128;
    const long z = blockIdx.z;

    const unsigned short* Bh = Bhp + z * strideB;
    const unsigned short* Bl = Blp + z * strideB;

    // fragment LDS byte offsets (swizzled), fixed per lane
    int aoff[4], boff[4];
    #pragma unroll
    for (int m = 0; m < 4; ++m) {
        int rt = wr * 64 + m * 16 + fr;
        aoff[m] = rt * 64 + ((fq ^ ((rt >> 1) & 3)) << 4);
        int ct = wc * 64 + m * 16 + fr;
        boff[m] = ct * 64 + ((fq ^ ((ct >> 1) & 3)) << 4);
    }

    ffrag acc[4][4] = {};

    const int sw_r = lane >> 2;   // staging row within 16-row group
    const int sw_c = lane & 3;    // staging chunk (linear dest)

    for (int k0 = 0; k0 < K; k0 += 32) {
        f4 x0, x1, x2, x3;
        int ar = tid >> 1;
        int kh = (tid & 1) << 4;
        if (AMODE == 0) {   // issue A fp32 loads before the barrier (overlap prev compute)
            const float* ap = (const float*)Ap + (brow + ar) * lda + k0 + kh;
            x0 = ((const f4*)ap)[0];
            x1 = ((const f4*)ap)[1];
            x2 = ((const f4*)ap)[2];
            x3 = ((const f4*)ap)[3];
        }
        __syncthreads();   // previous compute done reading LDS

        // stage B planes (global_load_lds, pre-swizzled source)
        #pragma unroll
        for (int i = 0; i < 2; ++i) {
            int lin = (wave + i * 4) << 10;            // 1KB per wave-inst
            int rr  = (lin >> 6) + sw_r;
            int cs  = sw_c ^ ((rr >> 1) & 3);
            gload_lds16((const char*)(Bh + (bcol + rr) * ldb + k0) + (cs << 4),
                        (char*)Bsh + lin);
            gload_lds16((const char*)(Bl + (bcol + rr) * ldb + k0) + (cs << 4),
                        (char*)Bsl + lin);
        }
        if (AMODE == 1) {
            const unsigned short* Ah = (const unsigned short*)Ap  + z * strideA;
            const unsigned short* Al = (const unsigned short*)Alp + z * strideA;
            #pragma unroll
            for (int i = 0; i < 2; ++i) {
                int lin = (wave + i * 4) << 10;
                int rr  = (lin >> 6) + sw_r;
                int cs  = sw_c ^ ((rr >> 1) & 3);
                gload_lds16((const char*)(Ah + (brow + rr) * lda + k0) + (cs << 4),
                            (char*)Ash + lin);
                gload_lds16((const char*)(Al + (brow + rr) * lda + k0) + (cs << 4),
                            (char*)Asl + lin);
            }
        } else {
            // convert fp32 A tile to hi/lo bf16 in LDS (swizzled ds_write)
            float xs[16] = {x0.x, x0.y, x0.z, x0.w, x1.x, x1.y, x1.z, x1.w,
                            x2.x, x2.y, x2.z, x2.w, x3.x, x3.y, x3.z, x3.w};
            #pragma unroll
            for (int g = 0; g < 4; ++g) {
                int e = kh + g * 4;
                unsigned short h[4], lo[4];
                #pragma unroll
                for (int j = 0; j < 4; ++j) {
                    float xx = xs[g * 4 + j];
                    h[j]  = f2bf(xx);
                    lo[j] = f2bf(xx - bf2f(h[j]));
                }
                int byte = ar * 64 + (((e >> 3) ^ ((ar >> 1) & 3)) << 4) + ((e & 7) << 1);
                uint2 hv, lv;
                hv.x = (unsigned)h[0]  | ((unsigned)h[1]  << 16);
                hv.y = (unsigned)h[2]  | ((unsigned)h[3]  << 16);
                lv.x = (unsigned)lo[0] | ((unsigned)lo[1] << 16);
                lv.y = (unsigned)lo[2] | ((unsigned)lo[3] << 16);
                *(uint2*)((char*)Ash + byte) = hv;
                *(uint2*)((char*)Asl + byte) = lv;
            }
        }
        __syncthreads();   // staging visible (vmcnt/lgkmcnt drained by barrier)

        bfrag ah[4], alf[4], bh[4], blf[4];
        #pragma unroll
        for (int m = 0; m < 4; ++m) {
            ah[m]  = *(const bfrag*)((const char*)Ash + aoff[m]);
            alf[m] = *(const bfrag*)((const char*)Asl + aoff[m]);
        }
        #pragma unroll
        for (int n = 0; n < 4; ++n) {
            bh[n]  = *(const bfrag*)((const char*)Bsh + boff[n]);
            blf[n] = *(const bfrag*)((const char*)Bsl + boff[n]);
        }
        #pragma unroll
        for (int m = 0; m < 4; ++m)
            #pragma unroll
            for (int n = 0; n < 4; ++n) {
                acc[m][n] = __builtin_amdgcn_mfma_f32_16x16x32_bf16(ah[m],  bh[n],  acc[m][n], 0, 0, 0);
                acc[m][n] = __builtin_amdgcn_mfma_f32_16x16x32_bf16(ah[m],  blf[n], acc[m][n], 0, 0, 0);
                acc[m][n] = __builtin_amdgcn_mfma_f32_16x16x32_bf16(alf[m], bh[n],  acc[m][n], 0, 0, 0);
            }
    }

    if (EPI == 0) {
        float* C = (float*)Cp + z * strideC;
        #pragma unroll
        for (int m = 0; m < 4; ++m) {
            long r0 = brow + wr * 64 + m * 16 + fq * 4;
            #pragma unroll
            for (int n = 0; n < 4; ++n) {
                long c = bcol + wc * 64 + n * 16 + fr;
                #pragma unroll
                for (int j = 0; j < 4; ++j)
                    C[(r0 + j) * ldc + c] = acc[m][n][j] * alpha;
            }
        }
    } else if (EPI == 1) {
        unsigned short* Ch = (unsigned short*)Cp;
        unsigned short* Cl = (unsigned short*)Clp;
        #pragma unroll
        for (int m = 0; m < 4; ++m) {
            long r0 = brow + wr * 64 + m * 16 + fq * 4;
            #pragma unroll
            for (int n = 0; n < 4; ++n) {
                long c = bcol + wc * 64 + n * 16 + fr;
                #pragma unroll
                for (int j = 0; j < 4; ++j) {
                    float xx = acc[m][n][j];
                    unsigned short h = f2bf(xx);
                    Ch[(r0 + j) * ldc + c] = h;
                    Cl[(r0 + j) * ldc + c] = f2bf(xx - bf2f(h));
                }
            }
        }
    } else {
        // EPI 2: write C^T as hi/lo planes, per-batch [1024][2048] (batch = row>>11)
        unsigned short* Ch = (unsigned short*)Cp;
        unsigned short* Cl = (unsigned short*)Clp;
        #pragma unroll
        for (int m = 0; m < 4; ++m) {
            long r0 = brow + wr * 64 + m * 16 + fq * 4;
            long b  = r0 >> 11, sr = r0 & 2047;
            #pragma unroll
            for (int n = 0; n < 4; ++n) {
                long c = bcol + wc * 64 + n * 16 + fr;
                unsigned short h[4], lo[4];
                #pragma unroll
                for (int j = 0; j < 4; ++j) {
                    float xx = acc[m][n][j];
                    h[j]  = f2bf(xx);
                    lo[j] = f2bf(xx - bf2f(h[j]));
                }
                uint2 hv, lv;
                hv.x = (unsigned)h[0]  | ((unsigned)h[1]  << 16);
                hv.y = (unsigned)h[2]  | ((unsigned)h[3]  << 16);
                lv.x = (unsigned)lo[0] | ((unsigned)lo[1] << 16);
                lv.y = (unsigned)lo[2] | ((unsigned)lo[3] << 16);
                *(uint2*)(Ch + (b << 21) + c * 2048 + sr) = hv;
                *(uint2*)(Cl + (b << 21) + c * 2048 + sr) = lv;
            }
        }
    }
}

// ---------------------------------------------------------------------------
// W [1024][1024] fp32 -> W^T hi/lo bf16 planes [1024][1024]
// ---------------------------------------------------------------------------
__global__ __launch_bounds__(256)
void transpose_split(const float* __restrict__ W,
                     unsigned short* __restrict__ Th,
                     unsigned short* __restrict__ Tl)
{
    __shared__ float t[64][65];
    const int tid = threadIdx.x;
    const int d0 = blockIdx.x * 64, e0 = blockIdx.y * 64;
    const int r = tid >> 4, c4 = (tid & 15) * 4;
    #pragma unroll
    for (int i = 0; i < 4; ++i) {
        f4 x = *(const f4*)(W + (long)(d0 + r + i * 16) * 1024 + e0 + c4);
        t[r + i * 16][c4 + 0] = x.x;
        t[r + i * 16][c4 + 1] = x.y;
        t[r + i * 16][c4 + 2] = x.z;
        t[r + i * 16][c4 + 3] = x.w;
    }
    __syncthreads();
    #pragma unroll
    for (int i = 0; i < 4; ++i) {
        int e = r + i * 16;
        unsigned short h[4], lo[4];
        #pragma unroll
        for (int j = 0; j < 4; ++j) {
            float xx = t[c4 + j][e];
            h[j]  = f2bf(xx);
            lo[j] = f2bf(xx - bf2f(h[j]));
        }
        uint2 hv, lv;
        hv.x = (unsigned)h[0]  | ((unsigned)h[1]  << 16);
        hv.y = (unsigned)h[2]  | ((unsigned)h[3]  << 16);
        lv.x = (unsigned)lo[0] | ((unsigned)lo[1] << 16);
        lv.y = (unsigned)lo[2] | ((unsigned)lo[3] << 16);
        long idx = (long)(e0 + e) * 1024 + d0 + c4;
        *(uint2*)(Th + idx) = hv;
        *(uint2*)(Tl + idx) = lv;
    }
}

// ---------------------------------------------------------------------------
// Row softmax (rows of 2048 fp32) -> in-place P as bf16 hi plane (bytes 0..4095)
// and lo plane (bytes 4096..8191) of each row.
// ---------------------------------------------------------------------------
__global__ __launch_bounds__(256)
void softmax_split(float* __restrict__ Sc)
{
    float* row = Sc + (size_t)blockIdx.x * 2048;
    const int tid = threadIdx.x;
    const int lane = tid & 63, wv = tid >> 6;
    __shared__ float red[8];

    f4 x0 = ((const f4*)row)[tid * 2];
    f4 x1 = ((const f4*)row)[tid * 2 + 1];

    float m = fmaxf(fmaxf(fmaxf(x0.x, x0.y), fmaxf(x0.z, x0.w)),
                    fmaxf(fmaxf(x1.x, x1.y), fmaxf(x1.z, x1.w)));
    #pragma unroll
    for (int o = 32; o > 0; o >>= 1) m = fmaxf(m, __shfl_xor(m, o));
    if (lane == 0) red[wv] = m;
    __syncthreads();
    m = fmaxf(fmaxf(red[0], red[1]), fmaxf(red[2], red[3]));

    float p[8];
    p[0] = __expf(x0.x - m); p[1] = __expf(x0.y - m);
    p[2] = __expf(x0.z - m); p[3] = __expf(x0.w - m);
    p[4] = __expf(x1.x - m); p[5] = __expf(x1.y - m);
    p[6] = __expf(x1.z - m); p[7] = __expf(x1.w - m);

    float s = ((p[0] + p[1]) + (p[2] + p[3])) + ((p[4] + p[5]) + (p[6] + p[7]));
    #pragma unroll
    for (int o = 32; o > 0; o >>= 1) s += __shfl_xor(s, o);
    if (lane == 0) red[4 + wv] = s;
    __syncthreads();
    s = (red[4] + red[5]) + (red[6] + red[7]);

    float inv = 1.0f / s;
    unsigned short h[8], lo[8];
    #pragma unroll
    for (int j = 0; j < 8; ++j) {
        float pv = p[j] * inv;
        h[j]  = f2bf(pv);
        lo[j] = f2bf(pv - bf2f(h[j]));
    }
    uint4 hv, lv;
    hv.x = (unsigned)h[0] | ((unsigned)h[1] << 16);
    hv.y = (unsigned)h[2] | ((unsigned)h[3] << 16);
    hv.z = (unsigned)h[4] | ((unsigned)h[5] << 16);
    hv.w = (unsigned)h[6] | ((unsigned)h[7] << 16);
    lv.x = (unsigned)lo[0] | ((unsigned)lo[1] << 16);
    lv.y = (unsigned)lo[2] | ((unsigned)lo[3] << 16);
    lv.z = (unsigned)lo[4] | ((unsigned)lo[5] << 16);
    lv.w = (unsigned)lo[6] | ((unsigned)lo[7] << 16);
    *(uint4*)((char*)row + tid * 16)        = hv;   // hi plane
    *(uint4*)((char*)row + 4096 + tid * 16) = lv;   // lo plane
}

// ---------------------------------------------------------------------------
// ws layout (bytes):
//   [0,12MB):   W^T hi/lo planes (3 x (2MB+2MB))
//   [12,76MB):  Qh,Ql,Kh,Kl  (16MB each)
//   [76,108MB): VTh,VTl      (16MB each, per-batch [1024][2048])
//   [108MB..):  scores fp32, nbat x 16MB (P hi/lo written in place)
// ---------------------------------------------------------------------------
extern "C" void kernel_launch(void* const* d_in, const int* in_sizes, int n_in,
                              void* d_out, int out_size, void* d_ws, size_t ws_size,
                              hipStream_t stream)
{
    const float* q  = (const float*)d_in[0];
    const float* k  = (const float*)d_in[1];
    const float* v  = (const float*)d_in[2];
    const float* Wq = (const float*)d_in[3];
    const float* Wk = (const float*)d_in[4];
    const float* Wv = (const float*)d_in[5];
    float* out = (float*)d_out;

    const long S = 2048, D = 1024;
    const long SD = S * D;       // 2,097,152
    const long SS = S * S;       // 4,194,304

    char* p = (char*)d_ws;
    size_t off = 0;
    unsigned short *WTh[3], *WTl[3];
    for (int i = 0; i < 3; ++i) {
        WTh[i] = (unsigned short*)(p + off); off += (size_t)2 << 20;
        WTl[i] = (unsigned short*)(p + off); off += (size_t)2 << 20;
    }
    unsigned short* Qh  = (unsigned short*)(p + off); off += (size_t)16 << 20;
    unsigned short* Ql  = (unsigned short*)(p + off); off += (size_t)16 << 20;
    unsigned short* Kh  = (unsigned short*)(p + off); off += (size_t)16 << 20;
    unsigned short* Kl  = (unsigned short*)(p + off); off += (size_t)16 << 20;
    unsigned short* VTh = (unsigned short*)(p + off); off += (size_t)16 << 20;
    unsigned short* VTl = (unsigned short*)(p + off); off += (size_t)16 << 20;
    float* Sc = (float*)(p + off);

    size_t avail = (ws_size > off) ? (ws_size - off) : 0;
    int nbat = (avail >= (size_t)64 << 20) ? 4 : ((avail >= (size_t)32 << 20) ? 2 : 1);

    dim3 blk(256);

    transpose_split<<<dim3(16, 16), blk, 0, stream>>>(Wq, WTh[0], WTl[0]);
    transpose_split<<<dim3(16, 16), blk, 0, stream>>>(Wk, WTh[1], WTl[1]);
    transpose_split<<<dim3(16, 16), blk, 0, stream>>>(Wv, WTh[2], WTl[2]);

    // Projections (M=8192, N=1024, K=1024)
    gemm_split<0, 1><<<dim3(8, 64, 1), blk, 0, stream>>>(
        q, nullptr, 1024, 0, WTh[0], WTl[0], 1024, 0, Qh, Ql, 1024, 0, 1024, 1.0f);
    gemm_split<0, 1><<<dim3(8, 64, 1), blk, 0, stream>>>(
        k, nullptr, 1024, 0, WTh[1], WTl[1], 1024, 0, Kh, Kl, 1024, 0, 1024, 1.0f);
    gemm_split<0, 2><<<dim3(8, 64, 1), blk, 0, stream>>>(
        v, nullptr, 1024, 0, WTh[2], WTl[2], 1024, 0, VTh, VTl, 0, 0, 1024, 1.0f);

    for (int b0 = 0; b0 < 4; b0 += nbat) {
        int nb = (4 - b0 < nbat) ? (4 - b0) : nbat;
        // scores = (Q @ K^T) / 32   [2048 x 2048] per batch
        gemm_split<1, 0><<<dim3(16, 16, nb), blk, 0, stream>>>(
            Qh + b0 * SD, Ql + b0 * SD, 1024, SD,
            Kh + b0 * SD, Kl + b0 * SD, 1024, SD,
            Sc, nullptr, 2048, SS, 1024, 0.03125f);
        // softmax rows -> P hi/lo in place
        softmax_split<<<dim3(2048 * nb), blk, 0, stream>>>(Sc);
        // out = P @ V   (A = P planes, pitch 4096 ushorts; B = V^T planes)
        gemm_split<1, 0><<<dim3(8, 16, nb), blk, 0, stream>>>(
            (unsigned short*)Sc, (unsigned short*)Sc + 2048, 4096, 2 * SS,
            VTh + b0 * SD, VTl + b0 * SD, 2048, SD,
            out + b0 * SD, nullptr, 1024, SD, 2048, 1.0f);
    }
}

// Round 4
// 514.195 us; speedup vs baseline: 3.1227x; 1.0996x over previous
//
#include <hip/hip_runtime.h>
#include <math.h>

typedef __attribute__((ext_vector_type(8))) short bfrag;   // 8 bf16 (4 VGPR)
typedef __attribute__((ext_vector_type(4))) float ffrag;   // 4 f32 acc
typedef __attribute__((ext_vector_type(4))) float f4;

static __device__ __forceinline__ unsigned short f2bf(float x) {
    unsigned u = __float_as_uint(x);
    return (unsigned short)((u + 0x7fffu + ((u >> 16) & 1u)) >> 16);
}
static __device__ __forceinline__ float bf2f(unsigned short h) {
    return __uint_as_float(((unsigned)h) << 16);
}

static __device__ __forceinline__ void gload_lds16(const void* g, void* l) {
    __builtin_amdgcn_global_load_lds(
        (const __attribute__((address_space(1))) void*)g,
        (__attribute__((address_space(3))) void*)l,
        16, 0, 0);
}

template<int N> static __device__ __forceinline__ void wait_vm() {
    asm volatile("s_waitcnt vmcnt(%0)" :: "n"(N) : "memory");
}
static __device__ __forceinline__ void lgkm0() {
    asm volatile("s_waitcnt lgkmcnt(0)" ::: "memory");
    __builtin_amdgcn_sched_barrier(0);
}

// ---------------------------------------------------------------------------
// 8-wave 256xBN split-bf16 GEMM, BK=32, plane-gated counted-vmcnt pipeline.
// C = alpha * (A @ B^T): A[M][K] as hi/lo bf16 planes (lda), B[N][K] hi/lo (ldb).
// acc = Ah*Bh + Ah*Bl + Al*Bh.
// 3 phases per K-tile: P0 hi*hi (gates Bh,Ah), P1 hi*lo (gates Bl), P2 lo*hi (gates Al).
// Prefetch of tile t+1 planes issued during tile t; vmcnt gate never drains to 0.
// LDS plane tiles [rows][32] bf16, row=64B=4 chunks; chunk' = chunk ^ ((row>>1)&3)
// (inverse swizzle applied on global source; linear gload_lds dest).
// EPI 0: C fp32 (alpha).  EPI 1: C hi/lo planes [M][ldc].  EPI 2: C^T hi/lo
// planes [1024][2048] per 2048-row batch (V^T).
// ---------------------------------------------------------------------------
template<int BN, int EPI>
__global__ __launch_bounds__(512, 2)
void gemm8(const unsigned short* __restrict__ Ahp, const unsigned short* __restrict__ Alp,
           long lda, long strideA,
           const unsigned short* __restrict__ Bhp, const unsigned short* __restrict__ Blp,
           long ldb, long strideB,
           void* __restrict__ Cp, void* __restrict__ Clp,
           long ldc, long strideC,
           int K, float alpha, int NXB)
{
    constexpr int NR   = BN / 64;      // n-frags per wave
    constexpr int LB   = BN / 128;     // B gloads per plane per thread
    constexpr int LDSA = 16384;
    constexpr int LDSB = BN * 64;
    constexpr int G0 = LB + 2;         // end-P2 gate (next P0 needs Bh,Ah)
    constexpr int G1 = 4 + LB;         // end-P0 gate (next P1 needs Bl)
    constexpr int G2 = 2 + 2 * LB;     // end-P1 gate (next P2 needs Al)

    __shared__ __align__(16) char smem[4 * LDSA + 4 * LDSB];

    const int tid  = threadIdx.x;
    const int lane = tid & 63;
    const int wave = tid >> 6;
    const int wr = wave >> 2, wc = wave & 3;
    const int fr = lane & 15, fq = lane >> 4;

    // XCD-chunked swizzle (gridDim.x % 8 == 0 for all our grids)
    int nwg = (int)gridDim.x;
    int id  = (int)blockIdx.x;
    id = (id & 7) * (nwg >> 3) + (id >> 3);
    const int bx = id % NXB, by = id / NXB;
    const long brow = (long)by * 256;
    const long bcol = (long)bx * BN;
    const long z = blockIdx.z;

    const char* gAh = (const char*)(Ahp + z * strideA + brow * lda);
    const char* gAl = (const char*)(Alp + z * strideA + brow * lda);
    const char* gBh = (const char*)(Bhp + z * strideB + bcol * ldb);
    const char* gBl = (const char*)(Blp + z * strideB + bcol * ldb);

    // staging source offsets (inverse-swizzled chunk) and dest (linear)
    int soffA[2], soffB[LB];
    #pragma unroll
    for (int j = 0; j < 2; ++j) {
        int idx = j * 512 + tid, row = idx >> 2;
        int cs = (tid & 3) ^ ((row >> 1) & 3);
        soffA[j] = row * (int)(lda * 2) + (cs << 4);
    }
    #pragma unroll
    for (int j = 0; j < LB; ++j) {
        int idx = j * 512 + tid, row = idx >> 2;
        int cs = (tid & 3) ^ ((row >> 1) & 3);
        soffB[j] = row * (int)(ldb * 2) + (cs << 4);
    }

    // fragment read offsets (swizzled)
    int aoff[8], boff[NR];
    #pragma unroll
    for (int m = 0; m < 8; ++m) {
        int rt = wr * 128 + m * 16 + fr;
        aoff[m] = rt * 64 + ((fq ^ ((rt >> 1) & 3)) << 4);
    }
    #pragma unroll
    for (int n = 0; n < NR; ++n) {
        int ct = wc * (BN / 4) + n * 16 + fr;
        boff[n] = ct * 64 + ((fq ^ ((ct >> 1) & 3)) << 4);
    }

    auto stageA = [&](const char* g, char* l, long ko) {
        #pragma unroll
        for (int j = 0; j < 2; ++j)
            gload_lds16(g + ko + soffA[j], l + ((j * 512 + tid) << 4));
    };
    auto stageB = [&](const char* g, char* l, long ko) {
        #pragma unroll
        for (int j = 0; j < LB; ++j)
            gload_lds16(g + ko + soffB[j], l + ((j * 512 + tid) << 4));
    };

    // prologue: stage tile 0 (order Bh, Ah, Bl, Al matches gate accounting)
    stageB(gBh, smem + 4 * LDSA, 0);
    stageA(gAh, smem, 0);
    stageB(gBl, smem + 4 * LDSA + 2 * LDSB, 0);
    stageA(gAl, smem + 2 * LDSA, 0);
    wait_vm<G0>();
    __builtin_amdgcn_s_barrier();

    ffrag acc[8][NR] = {};
    const int NT = K >> 5;

    for (int t = 0; t < NT; ++t) {
        const int par = t & 1, parn = par ^ 1;
        const long ko = (long)(((t + 1) < NT) ? (t + 1) : t) << 6;
        char* rAh = smem + par * LDSA;
        char* wAh = smem + parn * LDSA;
        char* rAl = smem + 2 * LDSA + par * LDSA;
        char* wAl = smem + 2 * LDSA + parn * LDSA;
        char* rBh = smem + 4 * LDSA + par * LDSB;
        char* wBh = smem + 4 * LDSA + parn * LDSB;
        char* rBl = smem + 4 * LDSA + 2 * LDSB + par * LDSB;
        char* wBl = smem + 4 * LDSA + 2 * LDSB + parn * LDSB;

        bfrag ah[8], bh[NR];
        // ---- P0: hi*hi ---------------------------------------------------
        #pragma unroll
        for (int m = 0; m < 8; ++m) ah[m] = *(const bfrag*)(rAh + aoff[m]);
        #pragma unroll
        for (int n = 0; n < NR; ++n) bh[n] = *(const bfrag*)(rBh + boff[n]);
        stageB(gBh, wBh, ko);
        stageA(gAh, wAh, ko);
        __builtin_amdgcn_s_barrier();
        lgkm0();
        __builtin_amdgcn_s_setprio(1);
        #pragma unroll
        for (int m = 0; m < 8; ++m)
            #pragma unroll
            for (int n = 0; n < NR; ++n)
                acc[m][n] = __builtin_amdgcn_mfma_f32_16x16x32_bf16(ah[m], bh[n], acc[m][n], 0, 0, 0);
        __builtin_amdgcn_s_setprio(0);
        wait_vm<G1>();
        __builtin_amdgcn_s_barrier();

        // ---- P1: hi*lo ---------------------------------------------------
        bfrag bl[NR];
        #pragma unroll
        for (int n = 0; n < NR; ++n) bl[n] = *(const bfrag*)(rBl + boff[n]);
        stageB(gBl, wBl, ko);
        __builtin_amdgcn_s_barrier();
        lgkm0();
        __builtin_amdgcn_s_setprio(1);
        #pragma unroll
        for (int m = 0; m < 8; ++m)
            #pragma unroll
            for (int n = 0; n < NR; ++n)
                acc[m][n] = __builtin_amdgcn_mfma_f32_16x16x32_bf16(ah[m], bl[n], acc[m][n], 0, 0, 0);
        __builtin_amdgcn_s_setprio(0);
        wait_vm<G2>();
        __builtin_amdgcn_s_barrier();

        // ---- P2: lo*hi ---------------------------------------------------
        bfrag al[8];
        #pragma unroll
        for (int m = 0; m < 8; ++m) al[m] = *(const bfrag*)(rAl + aoff[m]);
        stageA(gAl, wAl, ko);
        __builtin_amdgcn_s_barrier();
        lgkm0();
        __builtin_amdgcn_s_setprio(1);
        #pragma unroll
        for (int m = 0; m < 8; ++m)
            #pragma unroll
            for (int n = 0; n < NR; ++n)
                acc[m][n] = __builtin_amdgcn_mfma_f32_16x16x32_bf16(al[m], bh[n], acc[m][n], 0, 0, 0);
        __builtin_amdgcn_s_setprio(0);
        wait_vm<G0>();
        __builtin_amdgcn_s_barrier();
    }

    // drain remaining prefetch before LDS may be reallocated / epilogue
    wait_vm<0>();

    if (EPI == 0) {
        float* C = (float*)Cp + z * strideC;
        #pragma unroll
        for (int m = 0; m < 8; ++m) {
            long r0 = brow + wr * 128 + m * 16 + fq * 4;
            #pragma unroll
            for (int n = 0; n < NR; ++n) {
                long c = bcol + wc * (BN / 4) + n * 16 + fr;
                #pragma unroll
                for (int j = 0; j < 4; ++j)
                    C[(r0 + j) * ldc + c] = acc[m][n][j] * alpha;
            }
        }
    } else if (EPI == 1) {
        unsigned short* Ch = (unsigned short*)Cp;
        unsigned short* Cl = (unsigned short*)Clp;
        #pragma unroll
        for (int m = 0; m < 8; ++m) {
            long r0 = brow + wr * 128 + m * 16 + fq * 4;
            #pragma unroll
            for (int n = 0; n < NR; ++n) {
                long c = bcol + wc * (BN / 4) + n * 16 + fr;
                #pragma unroll
                for (int j = 0; j < 4; ++j) {
                    float xx = acc[m][n][j];
                    unsigned short h = f2bf(xx);
                    Ch[(r0 + j) * ldc + c] = h;
                    Cl[(r0 + j) * ldc + c] = f2bf(xx - bf2f(h));
                }
            }
        }
    } else {
        // C^T as hi/lo planes, per-batch [1024][2048] (batch = global row >> 11)
        unsigned short* Ch = (unsigned short*)Cp;
        unsigned short* Cl = (unsigned short*)Clp;
        #pragma unroll
        for (int m = 0; m < 8; ++m) {
            long r0 = brow + wr * 128 + m * 16 + fq * 4;
            long b = r0 >> 11, sr = r0 & 2047;
            #pragma unroll
            for (int n = 0; n < NR; ++n) {
                long c = bcol + wc * (BN / 4) + n * 16 + fr;
                unsigned short h[4], lo[4];
                #pragma unroll
                for (int j = 0; j < 4; ++j) {
                    float xx = acc[m][n][j];
                    h[j]  = f2bf(xx);
                    lo[j] = f2bf(xx - bf2f(h[j]));
                }
                uint2 hv, lv;
                hv.x = (unsigned)h[0]  | ((unsigned)h[1]  << 16);
                hv.y = (unsigned)h[2]  | ((unsigned)h[3]  << 16);
                lv.x = (unsigned)lo[0] | ((unsigned)lo[1] << 16);
                lv.y = (unsigned)lo[2] | ((unsigned)lo[3] << 16);
                *(uint2*)(Ch + (b << 21) + c * 2048 + sr) = hv;
                *(uint2*)(Cl + (b << 21) + c * 2048 + sr) = lv;
            }
        }
    }
}

// ---------------------------------------------------------------------------
// fp32 -> hi/lo bf16 planes (streaming split), n4 = element count / 4
// ---------------------------------------------------------------------------
__global__ __launch_bounds__(256)
void split_f32(const float* __restrict__ x, unsigned short* __restrict__ hi,
               unsigned short* __restrict__ lo, long n4)
{
    long i = (long)blockIdx.x * blockDim.x + threadIdx.x;
    long stride = (long)gridDim.x * blockDim.x;
    for (; i < n4; i += stride) {
        f4 v = ((const f4*)x)[i];
        unsigned short h[4], l[4];
        #pragma unroll
        for (int j = 0; j < 4; ++j) {
            float xx = v[j];
            h[j] = f2bf(xx);
            l[j] = f2bf(xx - bf2f(h[j]));
        }
        uint2 hv, lv;
        hv.x = (unsigned)h[0] | ((unsigned)h[1] << 16);
        hv.y = (unsigned)h[2] | ((unsigned)h[3] << 16);
        lv.x = (unsigned)l[0] | ((unsigned)l[1] << 16);
        lv.y = (unsigned)l[2] | ((unsigned)l[3] << 16);
        ((uint2*)hi)[i] = hv;
        ((uint2*)lo)[i] = lv;
    }
}

// ---------------------------------------------------------------------------
// W [1024][1024] fp32 -> W^T hi/lo bf16 planes [1024][1024]
// ---------------------------------------------------------------------------
__global__ __launch_bounds__(256)
void transpose_split(const float* __restrict__ W,
                     unsigned short* __restrict__ Th,
                     unsigned short* __restrict__ Tl)
{
    __shared__ float t[64][65];
    const int tid = threadIdx.x;
    const int d0 = blockIdx.x * 64, e0 = blockIdx.y * 64;
    const int r = tid >> 4, c4 = (tid & 15) * 4;
    #pragma unroll
    for (int i = 0; i < 4; ++i) {
        f4 x = *(const f4*)(W + (long)(d0 + r + i * 16) * 1024 + e0 + c4);
        t[r + i * 16][c4 + 0] = x.x;
        t[r + i * 16][c4 + 1] = x.y;
        t[r + i * 16][c4 + 2] = x.z;
        t[r + i * 16][c4 + 3] = x.w;
    }
    __syncthreads();
    #pragma unroll
    for (int i = 0; i < 4; ++i) {
        int e = r + i * 16;
        unsigned short h[4], lo[4];
        #pragma unroll
        for (int j = 0; j < 4; ++j) {
            float xx = t[c4 + j][e];
            h[j]  = f2bf(xx);
            lo[j] = f2bf(xx - bf2f(h[j]));
        }
        uint2 hv, lv;
        hv.x = (unsigned)h[0]  | ((unsigned)h[1]  << 16);
        hv.y = (unsigned)h[2]  | ((unsigned)h[3]  << 16);
        lv.x = (unsigned)lo[0] | ((unsigned)lo[1] << 16);
        lv.y = (unsigned)lo[2] | ((unsigned)lo[3] << 16);
        long idx = (long)(e0 + e) * 1024 + d0 + c4;
        *(uint2*)(Th + idx) = hv;
        *(uint2*)(Tl + idx) = lv;
    }
}

// ---------------------------------------------------------------------------
// Row softmax (2048 fp32) -> in-place P hi plane (bytes 0..4095) / lo plane
// (bytes 4096..8191) of each row.
// ---------------------------------------------------------------------------
__global__ __launch_bounds__(256)
void softmax_split(float* __restrict__ Sc)
{
    float* row = Sc + (size_t)blockIdx.x * 2048;
    const int tid = threadIdx.x;
    const int lane = tid & 63, wv = tid >> 6;
    __shared__ float red[8];

    f4 x0 = ((const f4*)row)[tid * 2];
    f4 x1 = ((const f4*)row)[tid * 2 + 1];

    float m = fmaxf(fmaxf(fmaxf(x0.x, x0.y), fmaxf(x0.z, x0.w)),
                    fmaxf(fmaxf(x1.x, x1.y), fmaxf(x1.z, x1.w)));
    #pragma unroll
    for (int o = 32; o > 0; o >>= 1) m = fmaxf(m, __shfl_xor(m, o));
    if (lane == 0) red[wv] = m;
    __syncthreads();
    m = fmaxf(fmaxf(red[0], red[1]), fmaxf(red[2], red[3]));

    float p[8];
    p[0] = __expf(x0.x - m); p[1] = __expf(x0.y - m);
    p[2] = __expf(x0.z - m); p[3] = __expf(x0.w - m);
    p[4] = __expf(x1.x - m); p[5] = __expf(x1.y - m);
    p[6] = __expf(x1.z - m); p[7] = __expf(x1.w - m);

    float s = ((p[0] + p[1]) + (p[2] + p[3])) + ((p[4] + p[5]) + (p[6] + p[7]));
    #pragma unroll
    for (int o = 32; o > 0; o >>= 1) s += __shfl_xor(s, o);
    if (lane == 0) red[4 + wv] = s;
    __syncthreads();
    s = (red[4] + red[5]) + (red[6] + red[7]);

    float inv = 1.0f / s;
    unsigned short h[8], lo[8];
    #pragma unroll
    for (int j = 0; j < 8; ++j) {
        float pv = p[j] * inv;
        h[j]  = f2bf(pv);
        lo[j] = f2bf(pv - bf2f(h[j]));
    }
    uint4 hv, lv;
    hv.x = (unsigned)h[0] | ((unsigned)h[1] << 16);
    hv.y = (unsigned)h[2] | ((unsigned)h[3] << 16);
    hv.z = (unsigned)h[4] | ((unsigned)h[5] << 16);
    hv.w = (unsigned)h[6] | ((unsigned)h[7] << 16);
    lv.x = (unsigned)lo[0] | ((unsigned)lo[1] << 16);
    lv.y = (unsigned)lo[2] | ((unsigned)lo[3] << 16);
    lv.z = (unsigned)lo[4] | ((unsigned)lo[5] << 16);
    lv.w = (unsigned)lo[6] | ((unsigned)lo[7] << 16);
    *(uint4*)((char*)row + tid * 16)        = hv;
    *(uint4*)((char*)row + 4096 + tid * 16) = lv;
}

// ---------------------------------------------------------------------------
// ws layout (bytes):
//   [0,12MB):    W^T hi/lo planes (3 x (2MB+2MB))
//   [12,76MB):   Qh,Ql,Kh,Kl (16MB each)
//   [76,108MB):  VTh,VTl (16MB each, per-batch [1024][2048])
//   [108,140MB): xh,xl split buffer (reused q->k->v)
//   [140MB..):   scores fp32 (nbat x 16MB); falls back to aliasing xh,xl.
// ---------------------------------------------------------------------------
extern "C" void kernel_launch(void* const* d_in, const int* in_sizes, int n_in,
                              void* d_out, int out_size, void* d_ws, size_t ws_size,
                              hipStream_t stream)
{
    const float* q  = (const float*)d_in[0];
    const float* k  = (const float*)d_in[1];
    const float* v  = (const float*)d_in[2];
    const float* Wq = (const float*)d_in[3];
    const float* Wk = (const float*)d_in[4];
    const float* Wv = (const float*)d_in[5];
    float* out = (float*)d_out;

    const long S = 2048, D = 1024;
    const long SD = S * D;
    const long SS = S * S;

    char* p = (char*)d_ws;
    size_t off = 0;
    unsigned short *WTh[3], *WTl[3];
    for (int i = 0; i < 3; ++i) {
        WTh[i] = (unsigned short*)(p + off); off += (size_t)2 << 20;
        WTl[i] = (unsigned short*)(p + off); off += (size_t)2 << 20;
    }
    unsigned short* Qh  = (unsigned short*)(p + off); off += (size_t)16 << 20;
    unsigned short* Ql  = (unsigned short*)(p + off); off += (size_t)16 << 20;
    unsigned short* Kh  = (unsigned short*)(p + off); off += (size_t)16 << 20;
    unsigned short* Kl  = (unsigned short*)(p + off); off += (size_t)16 << 20;
    unsigned short* VTh = (unsigned short*)(p + off); off += (size_t)16 << 20;
    unsigned short* VTl = (unsigned short*)(p + off); off += (size_t)16 << 20;
    unsigned short* xh  = (unsigned short*)(p + off); off += (size_t)16 << 20;
    unsigned short* xl  = (unsigned short*)(p + off); off += (size_t)16 << 20;

    float* Sc;
    int nbat;
    size_t avail = (ws_size > off) ? (ws_size - off) : 0;
    if (avail >= (size_t)64 << 20)      { Sc = (float*)(p + off); nbat = 4; }
    else if (avail >= (size_t)32 << 20) { Sc = (float*)(p + off); nbat = 2; }
    else                                { Sc = (float*)xh;        nbat = 2; }

    dim3 b256(256), b512(512);

    transpose_split<<<dim3(16, 16), b256, 0, stream>>>(Wq, WTh[0], WTl[0]);
    transpose_split<<<dim3(16, 16), b256, 0, stream>>>(Wk, WTh[1], WTl[1]);
    transpose_split<<<dim3(16, 16), b256, 0, stream>>>(Wv, WTh[2], WTl[2]);

    // Projections: split x, then 256-block 8-wave GEMM (M=8192,N=1024,K=1024)
    split_f32<<<dim3(2048), b256, 0, stream>>>(q, xh, xl, SD * 4 / 4);
    gemm8<128, 1><<<dim3(256, 1, 1), b512, 0, stream>>>(
        xh, xl, 1024, 0, WTh[0], WTl[0], 1024, 0, Qh, Ql, 1024, 0, 1024, 1.0f, 8);
    split_f32<<<dim3(2048), b256, 0, stream>>>(k, xh, xl, SD * 4 / 4);
    gemm8<128, 1><<<dim3(256, 1, 1), b512, 0, stream>>>(
        xh, xl, 1024, 0, WTh[1], WTl[1], 1024, 0, Kh, Kl, 1024, 0, 1024, 1.0f, 8);
    split_f32<<<dim3(2048), b256, 0, stream>>>(v, xh, xl, SD * 4 / 4);
    gemm8<128, 2><<<dim3(256, 1, 1), b512, 0, stream>>>(
        xh, xl, 1024, 0, WTh[2], WTl[2], 1024, 0, VTh, VTl, 0, 0, 1024, 1.0f, 8);

    for (int b0 = 0; b0 < 4; b0 += nbat) {
        int nb = (4 - b0 < nbat) ? (4 - b0) : nbat;
        // scores = (Q @ K^T) / 32   [2048 x 2048] per batch (BN=256)
        gemm8<256, 0><<<dim3(64, 1, nb), b512, 0, stream>>>(
            Qh + b0 * SD, Ql + b0 * SD, 1024, SD,
            Kh + b0 * SD, Kl + b0 * SD, 1024, SD,
            Sc, nullptr, 2048, SS, 1024, 0.03125f, 8);
        // softmax rows -> P hi/lo in place
        softmax_split<<<dim3(2048 * nb), b256, 0, stream>>>(Sc);
        // out = P @ V   (A = P planes pitch 4096; B = V^T planes; BN=128)
        gemm8<128, 0><<<dim3(64, 1, nb), b512, 0, stream>>>(
            (unsigned short*)Sc, (unsigned short*)Sc + 2048, 4096, 2 * SS,
            VTh + b0 * SD, VTl + b0 * SD, 2048, SD,
            out + b0 * SD, nullptr, 1024, SD, 2048, 1.0f, 8);
    }
}